// Round 5
// baseline (179.462 us; speedup 1.0000x reference)
//
#include <hip/hip_runtime.h>
#include <cstdint>

#define B_ROWS 16384
#define K_CODES 4096
#define D_DIM 256
#define NSPLIT 8
#define NT 64                                   // codes per tile
#define TPS (K_CODES / NSPLIT / NT)             // 8 tiles per split
#define TILE_BYTES (NT * D_DIM * 2)             // 32768
#define NROWBLK 64                              // 16384 / 256 rows per WG

typedef __attribute__((ext_vector_type(8))) short short8;
typedef __attribute__((ext_vector_type(4))) float floatx4;

__device__ __forceinline__ unsigned bfrne(float f) {   // rounded bf16 bits in high16
    unsigned u = __float_as_uint(f);
    return u + 0x7FFFu + ((u >> 16) & 1u);
}
__device__ __forceinline__ short f2bf_rne(float f) { return (short)(bfrne(f) >> 16); }

__device__ __forceinline__ void async_cp16(const void* g, void* l) {
    __builtin_amdgcn_global_load_lds(
        (const __attribute__((address_space(1))) unsigned*)g,
        (__attribute__((address_space(3))) unsigned*)l, 16, 0, 0);
}

// ---------- kernel 1: w -> bf16 in MFMA B-fragment order, wsq+bias, inits ----
// Fragment layout: byte(T,nb,s,lane) = T*32768 + ((nb*8+s)*64 + lane)*16,
// lane = q*16+lo16 holds w[T*64 + nb*16 + lo16][s*32 + q*8 .. +8) as 8 bf16.
// Staging becomes a contiguous global_load_lds copy; fragment ds_read_b128 is
// stride-1 (R4 measured: SQ_LDS_BANK_CONFLICT = 0).
__global__ __launch_bounds__(256) void prep_kernel(
        const float* __restrict__ w, char* __restrict__ wbf,
        float* __restrict__ wsqb, unsigned* __restrict__ minkey,
        unsigned* __restrict__ counter) {
    const int wave = threadIdx.x >> 6, lane = threadIdx.x & 63;
    const int rl = lane >> 5, c8 = lane & 31;           // 2 rows/wave, 32 chunks/row
    const int row = blockIdx.x * 8 + wave * 2 + rl;     // grid 512 * 8 = 4096 rows
    const float* src = w + (size_t)row * D_DIM + c8 * 8;
    floatx4 f0 = *(const floatx4*)src;
    floatx4 f1 = *(const floatx4*)(src + 4);
    uint4 pk;
    pk.x = (bfrne(f0[0]) >> 16) | (bfrne(f0[1]) & 0xFFFF0000u);
    pk.y = (bfrne(f0[2]) >> 16) | (bfrne(f0[3]) & 0xFFFF0000u);
    pk.z = (bfrne(f1[0]) >> 16) | (bfrne(f1[1]) & 0xFFFF0000u);
    pk.w = (bfrne(f1[2]) >> 16) | (bfrne(f1[3]) & 0xFFFF0000u);
    const int T = row >> 6, nb = (row >> 4) & 3, lo = row & 15;
    const int s = c8 >> 2, qq = c8 & 3;
    *(uint4*)(wbf + ((size_t)T * 2048 + (nb * 8 + s) * 64 + qq * 16 + lo) * 16) = pk;

    float ss = f0[0]*f0[0] + f0[1]*f0[1] + f0[2]*f0[2] + f0[3]*f0[3]
             + f1[0]*f1[0] + f1[1]*f1[1] + f1[2]*f1[2] + f1[3]*f1[3];
#pragma unroll
    for (int m = 1; m <= 16; m <<= 1) ss += __shfl_xor(ss, m, 64);  // within 32-group
    // +0.125 bias: score = wsq+0.125-2z.w provably positive (|2z.w| std ~4.5e-3,
    // 27 sigma margin) so fp32 bits order as u32.
    if (c8 == 0) wsqb[row] = ss + 0.125f;

    const int gid = blockIdx.x * 256 + threadIdx.x;     // ws re-poisoned: re-init
    if (gid < B_ROWS) minkey[gid] = 0xFFFFFFFFu;
    if (gid < NROWBLK) counter[gid] = 0u;
}

// ---------- kernel 2: MFMA argmin (Mw=64, dbuf async staging) + fused loss ---
// Wave owns 64 rows (4 M-blocks of 16): FLOP per LDS byte = Mw = 64 > 45
// (MFMA/LDS capacity ratio) -> MFMA-bound (R4 at Mw=32 was LDS-read-bound,
// MfmaUtil 21%). WG = 4 waves = 256 rows; NSPLIT=8 -> grid 64*8 = 512 WGs
// (2 blocks/CU: LDS 66 KB dbuf, VGPR ~220 -> 2 waves/SIMD).
__global__ __launch_bounds__(256, 2) void argmin_kernel(
        const float* __restrict__ z, const float* __restrict__ w,
        const char* __restrict__ wbf, const float* __restrict__ wsqb,
        unsigned* __restrict__ minkey, unsigned* __restrict__ counter,
        float* __restrict__ out) {
    __shared__ short lds[2][NT * D_DIM];     // 2 x 32 KiB
    __shared__ int sel[256];
    __shared__ int is_last;

    const int rowblk = blockIdx.x & (NROWBLK - 1);
    const int split  = blockIdx.x >> 6;       // 0..7
    const int wave = threadIdx.x >> 6, lane = threadIdx.x & 63;
    const int lo16 = lane & 15, q = lane >> 4;
    const int row_base = rowblk * 256 + wave * 64;

    // Persistent A fragments: A[m = lane&15][k = q*8 + j], 8 k-steps cover D=256
    short8 afrag[4][8];
#pragma unroll
    for (int mb = 0; mb < 4; ++mb) {
        const float* zr = z + (size_t)(row_base + mb * 16 + lo16) * D_DIM + q * 8;
#pragma unroll
        for (int s = 0; s < 8; ++s) {
            floatx4 g0 = *(const floatx4*)(zr + 32 * s);
            floatx4 g1 = *(const floatx4*)(zr + 32 * s + 4);
            short8 a;
            a[0] = f2bf_rne(g0[0]); a[1] = f2bf_rne(g0[1]);
            a[2] = f2bf_rne(g0[2]); a[3] = f2bf_rne(g0[3]);
            a[4] = f2bf_rne(g1[0]); a[5] = f2bf_rne(g1[1]);
            a[6] = f2bf_rne(g1[2]); a[7] = f2bf_rne(g1[3]);
            afrag[mb][s] = a;
        }
    }

    // packed argmin state: (score_bits & 0xFFFFF000) | col  (col = 12 bits)
    unsigned minu[4][4];
#pragma unroll
    for (int mb = 0; mb < 4; ++mb)
#pragma unroll
        for (int j = 0; j < 4; ++j) minu[mb][j] = 0xFFFFFFFFu;

    const int tbase = split * TPS;
    float wsqv[2];
    const char* gw = wbf + (size_t)wave * 8192 + (size_t)lane * 16;
    short* lb[2] = { &lds[0][wave * 4096], &lds[1][wave * 4096] };  // staging quarter
    short* rb[2] = { &lds[0][0], &lds[1][0] };                       // read base

    // per wave per tile: 8 global_load_lds (16B) + 1 wsq load = 9 vmem ops
#define PF(TILE, BUF) do { \
    const char* gsrc = gw + (size_t)(TILE) * TILE_BYTES; \
    _Pragma("unroll") \
    for (int i = 0; i < 8; ++i) \
        async_cp16(gsrc + i * 1024, lb[BUF] + i * 512); \
    wsqv[BUF] = wsqb[(TILE) * NT + lane]; \
} while (0)

    PF(tbase, 0);
    PF(tbase + 1, 1);

#define STEP(T_, BUF) do { \
    asm volatile("s_waitcnt vmcnt(9)" ::: "memory");  /* tile T_ staged; T_+1 in flight */ \
    asm volatile("s_barrier" ::: "memory"); \
    const int code_base = (tbase + (T_)) * NT; \
    const float wsv = wsqv[BUF]; \
    _Pragma("unroll") \
    for (int nb = 0; nb < 4; ++nb) { \
        float wsb = __shfl(wsv, nb * 16 + lo16, 64); \
        const short* lp = rb[BUF] + nb * 4096 + lane * 8; \
        short8 bf[8]; \
        _Pragma("unroll") \
        for (int s = 0; s < 8; ++s) bf[s] = *(const short8*)(lp + s * 512); \
        floatx4 acc0 = {0.f, 0.f, 0.f, 0.f}; \
        floatx4 acc1 = {0.f, 0.f, 0.f, 0.f}; \
        floatx4 acc2 = {0.f, 0.f, 0.f, 0.f}; \
        floatx4 acc3 = {0.f, 0.f, 0.f, 0.f}; \
        _Pragma("unroll") \
        for (int s = 0; s < 8; ++s) {  /* 4 independent chains: ILP for MFMA latency */ \
            acc0 = __builtin_amdgcn_mfma_f32_16x16x32_bf16(afrag[0][s], bf[s], acc0, 0, 0, 0); \
            acc1 = __builtin_amdgcn_mfma_f32_16x16x32_bf16(afrag[1][s], bf[s], acc1, 0, 0, 0); \
            acc2 = __builtin_amdgcn_mfma_f32_16x16x32_bf16(afrag[2][s], bf[s], acc2, 0, 0, 0); \
            acc3 = __builtin_amdgcn_mfma_f32_16x16x32_bf16(afrag[3][s], bf[s], acc3, 0, 0, 0); \
        } \
        const unsigned col = code_base + nb * 16 + lo16; \
        _Pragma("unroll") \
        for (int j = 0; j < 4; ++j) { \
            unsigned p; \
            p = (__float_as_uint(fmaf(-2.0f, acc0[j], wsb)) & 0xFFFFF000u) | col; \
            if (p < minu[0][j]) minu[0][j] = p; \
            p = (__float_as_uint(fmaf(-2.0f, acc1[j], wsb)) & 0xFFFFF000u) | col; \
            if (p < minu[1][j]) minu[1][j] = p; \
            p = (__float_as_uint(fmaf(-2.0f, acc2[j], wsb)) & 0xFFFFF000u) | col; \
            if (p < minu[2][j]) minu[2][j] = p; \
            p = (__float_as_uint(fmaf(-2.0f, acc3[j], wsb)) & 0xFFFFF000u) | col; \
            if (p < minu[3][j]) minu[3][j] = p; \
        } \
    } \
    asm volatile("s_barrier" ::: "memory");  /* all waves done reading buf */ \
    if ((T_) + 1 < TPS) { \
        const int nxt = ((T_) + 2 < TPS) ? (T_) + 2 : TPS - 1;  /* dummy keeps vmcnt invariant */ \
        PF(tbase + nxt, BUF); \
    } \
} while (0)

    for (int tt = 0; tt < TPS; tt += 2) {
        STEP(tt, 0);
        STEP(tt + 1, 1);
    }
#undef STEP
#undef PF

    // reduce packed min across the 16 lanes holding each row; merge via atomicMin
#pragma unroll
    for (int mb = 0; mb < 4; ++mb)
#pragma unroll
        for (int j = 0; j < 4; ++j) {
            unsigned v = minu[mb][j];
#pragma unroll
            for (int m = 1; m <= 8; m <<= 1) {
                unsigned ov = (unsigned)__shfl_xor((int)v, m, 64);
                if (ov < v) v = ov;
            }
            if (lo16 == 0) {
                const int row = row_base + mb * 16 + q * 4 + j;  // C: row=(lane>>4)*4+reg
                atomicMin(&minkey[row], v);
            }
        }

    // ---- last-WG-per-rowblock computes the exact fp32 loss for 256 rows ----
    __syncthreads();   // drains vmcnt; all atomicMins globally performed
    if (threadIdx.x == 0) {
        unsigned old = atomicAdd(&counter[rowblk], 1u);
        is_last = (old == NSPLIT - 1);
    }
    __syncthreads();
    if (!is_last) return;

    {
        unsigned k = atomicMin(&minkey[rowblk * 256 + threadIdx.x], 0xFFFFFFFFu);
        sel[threadIdx.x] = (int)(k & 0xFFFu);
    }
    __syncthreads();

#pragma unroll 4
    for (int r = 0; r < 64; ++r) {
        const int row = rowblk * 256 + wave * 64 + r;
        const int idx = sel[wave * 64 + r];
        floatx4 zv = *(const floatx4*)(z + (size_t)row * D_DIM + lane * 4);
        floatx4 wv = *(const floatx4*)(w + (size_t)idx * D_DIM + lane * 4);
        float d0 = zv[0] - wv[0], d1 = zv[1] - wv[1];
        float d2 = zv[2] - wv[2], d3 = zv[3] - wv[3];
        float s = d0 * d0 + d1 * d1 + d2 * d2 + d3 * d3;
#pragma unroll
        for (int m = 1; m < 64; m <<= 1) s += __shfl_xor(s, m, 64);
        if (lane == 0) out[row] = 1.25f * s;   // vq + 0.25 * commitment
    }
}

extern "C" void kernel_launch(void* const* d_in, const int* in_sizes, int n_in,
                              void* d_out, int out_size, void* d_ws, size_t ws_size,
                              hipStream_t stream) {
    const float* z = (const float*)d_in[0];
    const float* w = (const float*)d_in[1];
    float* out = (float*)d_out;

    char* ws = (char*)d_ws;
    char*     wbf     = ws;                                   // 2 MiB (frag layout)
    float*    wsqb    = (float*)(ws + 2097152);               // 16 KiB
    unsigned* minkey  = (unsigned*)(ws + 2097152 + 16384);    // 64 KiB
    unsigned* counter = (unsigned*)(ws + 2097152 + 16384 + 65536); // 256 B

    prep_kernel<<<512, 256, 0, stream>>>(w, wbf, wsqb, minkey, counter);
    argmin_kernel<<<NROWBLK * NSPLIT, 256, 0, stream>>>(z, w, wbf, wsqb, minkey, counter, out);
}

// Round 6
// 114.455 us; speedup vs baseline: 1.5680x; 1.5680x over previous
//
#include <hip/hip_runtime.h>
#include <cstdint>

#define B_ROWS 16384
#define K_CODES 4096
#define D_DIM 256
#define NSPLIT 4
#define NT 64                                   // codes per tile
#define TPS (K_CODES / NSPLIT / NT)             // 16 tiles per split
#define TILE_BYTES (NT * D_DIM)                 // 16384 (fp8)
#define NROWBLK 128                             // 16384 / 128 rows per WG
#define WSCALE 16384.0f                         // 2^14: w*WSCALE into e4m3 range
#define INV2SCALE 1.220703125e-4f               // 2 / 2^14

typedef __attribute__((ext_vector_type(4))) float floatx4;
typedef __attribute__((ext_vector_type(2))) long longx2;

__device__ __forceinline__ long pack_fp8x8(floatx4 g0, floatx4 g1) {
    int lo = __builtin_amdgcn_cvt_pk_fp8_f32(g0[0], g0[1], 0, 0);
    lo = __builtin_amdgcn_cvt_pk_fp8_f32(g0[2], g0[3], lo, 1);
    int hi = __builtin_amdgcn_cvt_pk_fp8_f32(g1[0], g1[1], 0, 0);
    hi = __builtin_amdgcn_cvt_pk_fp8_f32(g1[2], g1[3], hi, 1);
    return (long)(((unsigned long long)(unsigned)hi << 32) | (unsigned)lo);
}

__device__ __forceinline__ void async_cp16(const void* g, void* l) {
    __builtin_amdgcn_global_load_lds(
        (const __attribute__((address_space(1))) unsigned*)g,
        (__attribute__((address_space(3))) unsigned*)l, 16, 0, 0);
}

// ---------- kernel 1: w -> fp8 e4m3 (x2^14) in MFMA B-frag order, wsq, inits --
// Fragment layout: byte(T,nb,sp,lane,h) = T*16384 + ((nb*4+sp)*64 + lane)*16 + h*8
// lane = q*16+lo16; h-th half holds w[T*64+nb*16+lo16][(2sp+h)*32 + q*8 ..+8).
// Staging = contiguous global_load_lds; frag reads = stride-1 ds_read_b128
// (R4/R5 measured: SQ_LDS_BANK_CONFLICT = 0).
__global__ __launch_bounds__(256) void prep_kernel(
        const float* __restrict__ w, char* __restrict__ wbf,
        float* __restrict__ wsqb, unsigned* __restrict__ minkey,
        unsigned* __restrict__ counter) {
    const int wave = threadIdx.x >> 6, lane = threadIdx.x & 63;
    const int rl = lane >> 5, c8 = lane & 31;           // 2 rows/wave, 32 chunks/row
    const int row = blockIdx.x * 8 + wave * 2 + rl;     // grid 512 * 8 = 4096 rows
    const float* src = w + (size_t)row * D_DIM + c8 * 8;
    floatx4 f0 = *(const floatx4*)src;
    floatx4 f1 = *(const floatx4*)(src + 4);
    floatx4 s0 = f0 * WSCALE, s1 = f1 * WSCALE;
    long pk = pack_fp8x8(s0, s1);
    const int T = row >> 6, nb = (row >> 4) & 3, lo = row & 15;
    const int s = c8 >> 2, q = c8 & 3;                  // k-step, quad
    *(long*)(wbf + (size_t)T * 16384
             + ((nb * 4 + (s >> 1)) * 64 + q * 16 + lo) * 16 + (s & 1) * 8) = pk;

    float ss = f0[0]*f0[0] + f0[1]*f0[1] + f0[2]*f0[2] + f0[3]*f0[3]
             + f1[0]*f1[0] + f1[1]*f1[1] + f1[2]*f1[2] + f1[3]*f1[3];
#pragma unroll
    for (int m = 1; m <= 16; m <<= 1) ss += __shfl_xor(ss, m, 64);  // within 32-group
    // +0.125 bias: score = wsq+0.125-2z.w stays positive (|2z.w| <= ~0.012)
    // so fp32 bits order as u32 for the packed-key argmin.
    if (c8 == 0) wsqb[row] = ss + 0.125f;

    const int gid = blockIdx.x * 256 + threadIdx.x;     // ws re-poisoned: re-init
    if (gid < B_ROWS) minkey[gid] = 0xFFFFFFFFu;
    if (gid < NROWBLK) counter[gid] = 0u;
}

// ---------- kernel 2: fp8 MFMA argmin (dbuf async staging) + fused fp32 loss --
// Wave owns 32 rows (2 M-blocks). fp8 halves LDS bytes/tile: FLOP/LDS-byte =
// 2*Mw = 64 > 45 capacity ratio -> MFMA-bound (R4 bf16 at Mw=32 was LDS-bound).
// afrag 32 VGPRs (vs 64 bf16): total ~100, fits the observed 128 arch-VGPR cap
// under (256,2) (R5: Mw=64 bf16 needed ~200 -> 148 MB scratch spill).
__global__ __launch_bounds__(256, 2) void argmin_kernel(
        const float* __restrict__ z, const float* __restrict__ w,
        const char* __restrict__ wbf, const float* __restrict__ wsqb,
        unsigned* __restrict__ minkey, unsigned* __restrict__ counter,
        float* __restrict__ out) {
    __shared__ char lds[2][TILE_BYTES];      // 2 x 16 KiB
    __shared__ int sel[128];
    __shared__ int is_last;

    const int rowblk = blockIdx.x & 127;
    const int split  = blockIdx.x >> 7;       // 0..3
    const int wave = threadIdx.x >> 6, lane = threadIdx.x & 63;
    const int lo16 = lane & 15, q = lane >> 4;
    const int row_base = rowblk * 128 + wave * 32;

    // Persistent A fragments (fp8): A[m=lane&15][k=q*8+j] per 32-k step, 8 steps
    long afrag[2][8];
#pragma unroll
    for (int mb = 0; mb < 2; ++mb) {
        const float* zr = z + (size_t)(row_base + mb * 16 + lo16) * D_DIM + q * 8;
#pragma unroll
        for (int s = 0; s < 8; ++s) {
            floatx4 g0 = *(const floatx4*)(zr + 32 * s);
            floatx4 g1 = *(const floatx4*)(zr + 32 * s + 4);
            afrag[mb][s] = pack_fp8x8(g0, g1);
        }
    }

    // packed argmin state: (score_bits & 0xFFFFF000) | col  (col = 12 bits)
    unsigned minu[2][4];
#pragma unroll
    for (int mb = 0; mb < 2; ++mb)
#pragma unroll
        for (int j = 0; j < 4; ++j) minu[mb][j] = 0xFFFFFFFFu;

    const int tbase = split * TPS;
    float wsqv[2];
    const char* gw = wbf + (size_t)wave * 4096 + (size_t)lane * 16;
    char* lb[2] = { &lds[0][wave * 4096], &lds[1][wave * 4096] };  // staging quarter

    // per wave per tile: 4 global_load_lds (16B) + 1 wsq load = 5 vmem ops
#define PF(TILE, BUF) do { \
    const char* gsrc = gw + (size_t)(TILE) * TILE_BYTES; \
    _Pragma("unroll") \
    for (int i = 0; i < 4; ++i) \
        async_cp16(gsrc + i * 1024, lb[BUF] + i * 1024); \
    wsqv[BUF] = wsqb[(TILE) * NT + lane]; \
} while (0)

    PF(tbase, 0);
    PF(tbase + 1, 1);

#define STEP(T_, BUF) do { \
    asm volatile("s_waitcnt vmcnt(5)" ::: "memory");  /* tile T_ staged; T_+1 in flight */ \
    asm volatile("s_barrier" ::: "memory"); \
    const int code_base = (tbase + (T_)) * NT; \
    const float wsv = wsqv[BUF]; \
    _Pragma("unroll") \
    for (int nb = 0; nb < 4; ++nb) { \
        float wsb = __shfl(wsv, nb * 16 + lo16, 64); \
        const char* lp = &lds[BUF][nb * 4096 + lane * 16]; \
        longx2 bfr[4]; \
        _Pragma("unroll") \
        for (int sp = 0; sp < 4; ++sp) bfr[sp] = *(const longx2*)(lp + sp * 1024); \
        floatx4 acc0 = {0.f, 0.f, 0.f, 0.f}; \
        floatx4 acc1 = {0.f, 0.f, 0.f, 0.f}; \
        _Pragma("unroll") \
        for (int sp = 0; sp < 4; ++sp) { \
            acc0 = __builtin_amdgcn_mfma_f32_16x16x32_fp8_fp8(afrag[0][2*sp],   bfr[sp][0], acc0, 0, 0, 0); \
            acc1 = __builtin_amdgcn_mfma_f32_16x16x32_fp8_fp8(afrag[1][2*sp],   bfr[sp][0], acc1, 0, 0, 0); \
            acc0 = __builtin_amdgcn_mfma_f32_16x16x32_fp8_fp8(afrag[0][2*sp+1], bfr[sp][1], acc0, 0, 0, 0); \
            acc1 = __builtin_amdgcn_mfma_f32_16x16x32_fp8_fp8(afrag[1][2*sp+1], bfr[sp][1], acc1, 0, 0, 0); \
        } \
        const unsigned col = code_base + nb * 16 + lo16; \
        _Pragma("unroll") \
        for (int j = 0; j < 4; ++j) { \
            unsigned p; \
            p = (__float_as_uint(fmaf(-INV2SCALE, acc0[j], wsb)) & 0xFFFFF000u) | col; \
            if (p < minu[0][j]) minu[0][j] = p; \
            p = (__float_as_uint(fmaf(-INV2SCALE, acc1[j], wsb)) & 0xFFFFF000u) | col; \
            if (p < minu[1][j]) minu[1][j] = p; \
        } \
    } \
    asm volatile("s_barrier" ::: "memory");  /* all waves done reading buf */ \
    if ((T_) + 1 < TPS) { \
        const int nxt = ((T_) + 2 < TPS) ? (T_) + 2 : TPS - 1;  /* dummy keeps vmcnt invariant */ \
        PF(tbase + nxt, BUF); \
    } \
} while (0)

    for (int tt = 0; tt < TPS; tt += 2) {
        STEP(tt, 0);
        STEP(tt + 1, 1);
    }
#undef STEP
#undef PF

    // reduce packed min across the 16 lanes holding each row; merge via atomicMin
#pragma unroll
    for (int mb = 0; mb < 2; ++mb)
#pragma unroll
        for (int j = 0; j < 4; ++j) {
            unsigned v = minu[mb][j];
#pragma unroll
            for (int m = 1; m <= 8; m <<= 1) {
                unsigned ov = (unsigned)__shfl_xor((int)v, m, 64);
                if (ov < v) v = ov;
            }
            if (lo16 == 0) {
                const int row = row_base + mb * 16 + q * 4 + j;  // C: row=(lane>>4)*4+reg
                atomicMin(&minkey[row], v);
            }
        }

    // ---- last-WG-per-rowblock computes the exact fp32 loss for 128 rows ----
    __syncthreads();   // drains vmcnt; all atomicMins globally performed
    if (threadIdx.x == 0) {
        unsigned old = atomicAdd(&counter[rowblk], 1u);
        is_last = (old == NSPLIT - 1);
    }
    __syncthreads();
    if (!is_last) return;

    if (threadIdx.x < 128) {
        unsigned k = atomicMin(&minkey[rowblk * 128 + threadIdx.x], 0xFFFFFFFFu);
        sel[threadIdx.x] = (int)(k & 0xFFFu);
    }
    __syncthreads();

#pragma unroll 4
    for (int r = 0; r < 32; ++r) {
        const int row = rowblk * 128 + wave * 32 + r;
        const int idx = sel[wave * 32 + r];
        floatx4 zv = *(const floatx4*)(z + (size_t)row * D_DIM + lane * 4);
        floatx4 wv = *(const floatx4*)(w + (size_t)idx * D_DIM + lane * 4);
        float d0 = zv[0] - wv[0], d1 = zv[1] - wv[1];
        float d2 = zv[2] - wv[2], d3 = zv[3] - wv[3];
        float s = d0 * d0 + d1 * d1 + d2 * d2 + d3 * d3;
#pragma unroll
        for (int m = 1; m < 64; m <<= 1) s += __shfl_xor(s, m, 64);
        if (lane == 0) out[row] = 1.25f * s;   // vq + 0.25 * commitment (identical sums)
    }
}

extern "C" void kernel_launch(void* const* d_in, const int* in_sizes, int n_in,
                              void* d_out, int out_size, void* d_ws, size_t ws_size,
                              hipStream_t stream) {
    const float* z = (const float*)d_in[0];
    const float* w = (const float*)d_in[1];
    float* out = (float*)d_out;

    char* ws = (char*)d_ws;
    char*     wbf     = ws;                                   // 1 MiB (fp8 frag layout)
    float*    wsqb    = (float*)(ws + 1048576);               // 16 KiB
    unsigned* minkey  = (unsigned*)(ws + 1048576 + 16384);    // 64 KiB
    unsigned* counter = (unsigned*)(ws + 1048576 + 16384 + 65536); // 512 B

    prep_kernel<<<512, 256, 0, stream>>>(w, wbf, wsqb, minkey, counter);
    argmin_kernel<<<NROWBLK * NSPLIT, 256, 0, stream>>>(z, w, wbf, wsqb, minkey, counter, out);
}